// Round 3
// baseline (421.124 us; speedup 1.0000x reference)
//
#include <hip/hip_runtime.h>
#include <hip/hip_bf16.h>
#include <math.h>

// Problem constants (fixed by setup_inputs):
// B=16, T=8, NT=128, C=512, H=W=28, HW=784, c8=64
constexpr int NT  = 128;
constexpr int C   = 512;
constexpr int HW  = 784;      // 28*28 = 196 float4
constexpr int C8  = 64;
constexpr int TT  = 8;
constexpr int BB  = 16;
constexpr float EPS = 1e-5f;

typedef float v4f __attribute__((ext_vector_type(4)));   // native vec for nontemporal

// K1: spatial mean. One wave per 2 rows (more loads in flight).
// Block = 256 threads = 4 waves = 8 rows; grid = 65536/8 = 8192.
__global__ void k_mean(const float* __restrict__ x, float* __restrict__ xv) {
    const int wave = threadIdx.x >> 6;
    const int lane = threadIdx.x & 63;
    const size_t r0 = ((size_t)blockIdx.x * 4 + wave) * 2;
    const float4* p0 = (const float4*)(x + r0 * HW);
    const float4* p1 = (const float4*)(x + (r0 + 1) * HW);
    float s0 = 0.f, s1 = 0.f;
    for (int j = lane; j < HW / 4; j += 64) {           // 196 float4 per row
        float4 a = p0[j];
        float4 b = p1[j];
        s0 += a.x + a.y + a.z + a.w;
        s1 += b.x + b.y + b.z + b.w;
    }
    #pragma unroll
    for (int off = 32; off; off >>= 1) {
        s0 += __shfl_xor(s0, off);
        s1 += __shfl_xor(s1, off);
    }
    if (lane == 0) {
        xv[r0]     = s0 * (1.0f / HW);
        xv[r0 + 1] = s1 * (1.0f / HW);
    }
}

// K2: left/right = relu(bn(xv @ w^T)). Wave-per-output reduction, fully
// coalesced weight reads (lane ℓ reads w[j*512 + ℓ*8 .. +7] → 2 KB/instr).
// grid = 256 blocks: bt = bid>>1, side = bid&1. 4 waves × 16 outputs each.
__global__ void k_lr(const float* __restrict__ xv,
                     const float* __restrict__ w1,
                     const float* __restrict__ g1, const float* __restrict__ b1,
                     const float* __restrict__ m1, const float* __restrict__ v1,
                     const float* __restrict__ w2,
                     const float* __restrict__ g2, const float* __restrict__ b2,
                     const float* __restrict__ m2, const float* __restrict__ v2,
                     float* __restrict__ lr) {
    const int bt   = blockIdx.x >> 1;
    const int side = blockIdx.x & 1;
    const int wave = threadIdx.x >> 6;
    const int lane = threadIdx.x & 63;

    const float* wb = side ? w2 : w1;
    const float* gg = side ? g2 : g1;
    const float* bb = side ? b2 : b1;
    const float* mm = side ? m2 : m1;
    const float* vv = side ? v2 : v1;

    // hoist the input row fragment (same for all outputs of this block)
    const float4* xr = (const float4*)(xv + (size_t)bt * C);
    const float4 x0 = xr[lane * 2];
    const float4 x1 = xr[lane * 2 + 1];

    const int j0 = wave * 16;
    #pragma unroll
    for (int jj = 0; jj < 16; jj += 2) {
        const int ja = j0 + jj, jb2 = j0 + jj + 1;
        const float4* wa = (const float4*)(wb + (size_t)ja * C);
        const float4* wc = (const float4*)(wb + (size_t)jb2 * C);
        float4 a0 = wa[lane * 2], a1 = wa[lane * 2 + 1];
        float4 c0 = wc[lane * 2], c1 = wc[lane * 2 + 1];
        float sa = a0.x * x0.x + a0.y * x0.y + a0.z * x0.z + a0.w * x0.w
                 + a1.x * x1.x + a1.y * x1.y + a1.z * x1.z + a1.w * x1.w;
        float sc = c0.x * x0.x + c0.y * x0.y + c0.z * x0.z + c0.w * x0.w
                 + c1.x * x1.x + c1.y * x1.y + c1.z * x1.z + c1.w * x1.w;
        #pragma unroll
        for (int off = 32; off; off >>= 1) {
            sa += __shfl_xor(sa, off);
            sc += __shfl_xor(sc, off);
        }
        if (lane == 0) {
            float ya = (sa - mm[ja])  * rsqrtf(vv[ja]  + EPS) * gg[ja]  + bb[ja];
            float yc = (sc - mm[jb2]) * rsqrtf(vv[jb2] + EPS) * gg[jb2] + bb[jb2];
            lr[bt * 2 * C8 + side * C8 + ja]  = fmaxf(ya, 0.f);
            lr[bt * 2 * C8 + side * C8 + jb2] = fmaxf(yc, 0.f);
        }
    }
}

// K3: temporal scan. One wave per batch (16 blocks x 64 threads).
// diff[b,t] = left[b,t] - right[b,t+1] (t<T-1), else 1.  state0 = ones.
// g = sigmoid(dot(d_t,gw0)+dot(state,gw1)+gb)  (scalar per (b,t))
// state = g*d_t + (1-g)*state ; New[b,t,:] = state
__global__ void k_scan(const float* __restrict__ lr,
                       const float* __restrict__ gamma_w,
                       const float* __restrict__ gamma_b,
                       float* __restrict__ Nw) {
    const int b = blockIdx.x;    // 0..15
    const int j = threadIdx.x;   // 0..63
    const float gw0 = gamma_w[j];
    const float gw1 = gamma_w[C8 + j];
    const float gb  = gamma_b[0];

    float d[TT];
    #pragma unroll
    for (int t = 0; t < TT - 1; ++t)
        d[t] = lr[(b * TT + t) * (2 * C8) + j]
             - lr[(b * TT + t + 1) * (2 * C8) + C8 + j];
    d[TT - 1] = 1.0f;

    float state = 1.0f;
    #pragma unroll
    for (int t = 0; t < TT; ++t) {
        float part = d[t] * gw0 + state * gw1;
        #pragma unroll
        for (int off = 32; off; off >>= 1) part += __shfl_xor(part, off);
        const float g = 1.f / (1.f + expf(-(part + gb)));
        state = d[t] * g + state * (1.f - g);
        Nw[(b * TT + t) * C8 + j] = state;
    }
}

// K4: sig[bt,c] = sigmoid(dot(New[bt], Wa_w[c]) + Wa_b[c]).
// Octet-per-output: lane ℓ covers k-chunk (ℓ&7)*8..+7 of output base+(ℓ>>3).
// Weight reads are 2 KB contiguous per wave instruction. grid = 128, 256 thr.
__global__ void k_att(const float* __restrict__ Nw,
                      const float* __restrict__ Wa_w,
                      const float* __restrict__ Wa_b,
                      float* __restrict__ sig) {
    const int bt   = blockIdx.x;
    const int wave = threadIdx.x >> 6;
    const int lane = threadIdx.x & 63;
    const int g    = lane >> 3;    // which output in the octet (0..7)
    const int k8   = lane & 7;     // which 8-float chunk of the 64-dot

    // hoist New row fragment (same for every iteration)
    const float4* nr = (const float4*)(Nw + (size_t)bt * C8);
    const float4 n0 = nr[k8 * 2];
    const float4 n1 = nr[k8 * 2 + 1];

    #pragma unroll
    for (int it = 0; it < 16; ++it) {
        const int c = wave * 128 + it * 8 + g;           // 512 outputs / 4 waves
        const float4* wr = (const float4*)(Wa_w + (size_t)c * C8);
        float4 w0 = wr[k8 * 2], w1 = wr[k8 * 2 + 1];
        float acc = w0.x * n0.x + w0.y * n0.y + w0.z * n0.z + w0.w * n0.w
                  + w1.x * n1.x + w1.y * n1.y + w1.z * n1.z + w1.w * n1.w;
        acc += __shfl_xor(acc, 1);
        acc += __shfl_xor(acc, 2);
        acc += __shfl_xor(acc, 4);
        if (k8 == 0)
            sig[(size_t)bt * C + c] = 1.f / (1.f + expf(-(acc + Wa_b[c])));
    }
}

// K5: out[row,:] = x[row,:] * sig[row]. One wave per 2 rows; nontemporal
// stores so the output stream doesn't evict x from L3.
__global__ void k_scale(const float* __restrict__ x,
                        const float* __restrict__ sig,
                        float* __restrict__ out) {
    const int wave = threadIdx.x >> 6;
    const int lane = threadIdx.x & 63;
    const size_t r0 = ((size_t)blockIdx.x * 4 + wave) * 2;
    const float s0 = sig[r0];
    const float s1 = sig[r0 + 1];
    const float4* p0 = (const float4*)(x + r0 * HW);
    const float4* p1 = (const float4*)(x + (r0 + 1) * HW);
    v4f* o0 = (v4f*)(out + r0 * HW);
    v4f* o1 = (v4f*)(out + (r0 + 1) * HW);
    for (int j = lane; j < HW / 4; j += 64) {
        float4 a = p0[j];
        float4 b = p1[j];
        v4f av = {a.x * s0, a.y * s0, a.z * s0, a.w * s0};
        v4f bv = {b.x * s1, b.y * s1, b.z * s1, b.w * s1};
        __builtin_nontemporal_store(av, o0 + j);
        __builtin_nontemporal_store(bv, o1 + j);
    }
}

extern "C" void kernel_launch(void* const* d_in, const int* in_sizes, int n_in,
                              void* d_out, int out_size, void* d_ws, size_t ws_size,
                              hipStream_t stream) {
    const float* x     = (const float*)d_in[0];
    const float* w1    = (const float*)d_in[1];
    const float* bn1_g = (const float*)d_in[2];
    const float* bn1_b = (const float*)d_in[3];
    const float* bn1_m = (const float*)d_in[4];
    const float* bn1_v = (const float*)d_in[5];
    const float* w2    = (const float*)d_in[6];
    const float* bn2_g = (const float*)d_in[7];
    const float* bn2_b = (const float*)d_in[8];
    const float* bn2_m = (const float*)d_in[9];
    const float* bn2_v = (const float*)d_in[10];
    const float* Wa_w  = (const float*)d_in[11];
    const float* Wa_b  = (const float*)d_in[12];
    const float* gamma_w = (const float*)d_in[13];
    const float* gamma_b = (const float*)d_in[14];
    float* out = (float*)d_out;

    // workspace layout (floats): xv[65536] | lr[16384] | New[8192] | sig[65536]
    float* ws  = (float*)d_ws;
    float* xv  = ws;
    float* lr  = xv + NT * C;
    float* Nw  = lr + NT * 2 * C8;
    float* sig = Nw + NT * C8;

    const int rows = NT * C;                 // 65536
    k_mean <<<rows / 8, 256, 0, stream>>>(x, xv);
    k_lr   <<<NT * 2, 256, 0, stream>>>(xv, w1, bn1_g, bn1_b, bn1_m, bn1_v,
                                            w2, bn2_g, bn2_b, bn2_m, bn2_v, lr);
    k_scan <<<BB, 64, 0, stream>>>(lr, gamma_w, gamma_b, Nw);
    k_att  <<<NT, 256, 0, stream>>>(Nw, Wa_w, Wa_b, sig);
    k_scale<<<rows / 8, 256, 0, stream>>>(x, sig, out);
}